// Round 1
// baseline (227.257 us; speedup 1.0000x reference)
//
#include <hip/hip_runtime.h>
#include <hip/hip_bf16.h>
#include <math.h>

// Problem constants (from reference)
#define R_CHK   144
#define N_VAR   576
#define BATCH   512
#define ITERS   3
#define NLEV    16
#define ROW_DEG 15
#define N_EDGE  (R_CHK * ROW_DEG)   // 2160
#define MAXDEG  32

// ---------------------------------------------------------------------------
// Kernel A: build sparse index from H into workspace.
//   edge_cols[e]          : column of edge e (e = row*15 + k, cols ascending)
//   col_len[v]            : number of edges incident to column v
//   col_edge[v*MAXDEG+j]  : edge ids of column v, ascending row order
// ---------------------------------------------------------------------------
__global__ void build_index_kernel(const float* __restrict__ H,
                                   int* __restrict__ edge_cols,
                                   int* __restrict__ col_len,
                                   int* __restrict__ col_edge) {
    __shared__ int s_ecol[N_EDGE];
    const int t = threadIdx.x;   // 576 threads

    if (t < R_CHK) {
        int k = 0;
        const float* row = H + t * N_VAR;
        for (int v = 0; v < N_VAR; ++v) {
            if (row[v] > 0.5f) {
                if (k < ROW_DEG) s_ecol[t * ROW_DEG + k] = v;
                ++k;
            }
        }
    }
    __syncthreads();

    for (int e = t; e < N_EDGE; e += blockDim.x) edge_cols[e] = s_ecol[e];

    if (t < N_VAR) {
        int n = 0;
        for (int e = 0; e < N_EDGE; ++e) {          // ascending e = ascending row
            if (s_ecol[e] == t) {
                if (n < MAXDEG) col_edge[t * MAXDEG + n] = e;
                ++n;
            }
        }
        col_len[t] = (n < MAXDEG) ? n : MAXDEG;
    }
}

// ---------------------------------------------------------------------------
// Kernel B: one block per batch element; all messages live in LDS.
// ---------------------------------------------------------------------------
__launch_bounds__(256)
__global__ void decode_kernel(const float* __restrict__ r,
                              const float* __restrict__ alpha,
                              const float* __restrict__ beta,
                              const float* __restrict__ eta,
                              const float* __restrict__ qk,
                              const int* __restrict__ edge_cols,
                              const int* __restrict__ col_len,
                              const int* __restrict__ col_edge,
                              float* __restrict__ out) {
    __shared__ float sM[N_EDGE];
    __shared__ float sE[N_EDGE];
    __shared__ float scol[N_VAR];
    __shared__ float sr[N_VAR];
    __shared__ int   secol[N_EDGE];
    __shared__ float sqk[NLEV];
    __shared__ float sbnd[NLEV - 1];

    const int b = blockIdx.x;
    const int t = threadIdx.x;

    if (t < NLEV) sqk[t] = qk[t];
    __syncthreads();
    if (t < NLEV - 1) sbnd[t] = 0.5f * (sqk[t] + sqk[t + 1]);   // same as jnp
    for (int v = t; v < N_VAR; v += 256) sr[v] = r[b * N_VAR + v];
    for (int e = t; e < N_EDGE; e += 256) secol[e] = edge_cols[e];
    __syncthreads();
    for (int e = t; e < N_EDGE; e += 256) sM[e] = sr[secol[e]];  // M = H*r
    __syncthreads();

    for (int it = 0; it < ITERS; ++it) {
        const float a   = alpha[it];
        const float bta = beta[it];
        const float et  = eta[it];

        // ---- row phase: check-to-variable messages -----------------------
        if (t < R_CHK) {
            const int base = t * ROW_DEG;
            float vals[ROW_DEG];
            float m1 = INFINITY, m2 = INFINITY;
            float prod = 1.0f;
#pragma unroll
            for (int k = 0; k < ROW_DEG; ++k) {
                float M = sM[base + k];
                vals[k] = M;
                float ab = fabsf(M);
                if (ab < m1)      { m2 = m1; m1 = ab; }
                else if (ab < m2) { m2 = ab; }
                float s = (M > 0.0f) ? 1.0f : ((M < 0.0f) ? -1.0f : 0.0f);
                prod *= s;
            }
#pragma unroll
            for (int k = 0; k < ROW_DEG; ++k) {
                float M  = vals[k];
                float ab = fabsf(M);
                float mexcl = (ab == m1) ? m2 : m1;   // exact ==, matches jnp.where(mag==m1,...)
                float s  = (M > 0.0f) ? 1.0f : ((M < 0.0f) ? -1.0f : 0.0f);
                float E  = ((a * prod) * s) * fmaxf(mexcl - bta, 0.0f);
                // quantize: idx = #{ bnd[j] < eta*E }  (searchsorted side='left')
                float y = et * E;
                int idx = 0;
#pragma unroll
                for (int j = 0; j < NLEV - 1; ++j) idx += (y > sbnd[j]) ? 1 : 0;
                sE[base + k] = sqk[idx];
            }
        }
        __syncthreads();

        // ---- column phase: sum over checks (ascending row order) ---------
        for (int v = t; v < N_VAR; v += 256) {
            float sum = 0.0f;
            int n = col_len[v];
            const int* ce = col_edge + v * MAXDEG;
            for (int j = 0; j < n; ++j) sum += sE[ce[j]];
            scol[v] = sum;
        }
        __syncthreads();

        // ---- variable-to-check update (dead after last iteration) --------
        if (it < ITERS - 1) {
            for (int e = t; e < N_EDGE; e += 256) {
                int v = secol[e];
                float M = (sr[v] + scol[v]) - sE[e];
                float y = et * M;
                int idx = 0;
#pragma unroll
                for (int j = 0; j < NLEV - 1; ++j) idx += (y > sbnd[j]) ? 1 : 0;
                sM[e] = sqk[idx];
            }
            __syncthreads();
        }
    }

    // out = r + sum(E, axis=1)  (== r + col from last iteration)
    for (int v = t; v < N_VAR; v += 256) out[b * N_VAR + v] = sr[v] + scol[v];
}

// ---------------------------------------------------------------------------
extern "C" void kernel_launch(void* const* d_in, const int* in_sizes, int n_in,
                              void* d_out, int out_size, void* d_ws, size_t ws_size,
                              hipStream_t stream) {
    const float* r     = (const float*)d_in[0];
    const float* alpha = (const float*)d_in[1];
    const float* beta  = (const float*)d_in[2];
    const float* eta   = (const float*)d_in[3];
    const float* qk    = (const float*)d_in[4];
    const float* H     = (const float*)d_in[5];
    float* out = (float*)d_out;

    // workspace layout
    int* edge_cols = (int*)d_ws;                    // N_EDGE ints
    int* col_len   = edge_cols + N_EDGE;            // N_VAR ints
    int* col_edge  = col_len + N_VAR;               // N_VAR*MAXDEG ints

    build_index_kernel<<<1, N_VAR, 0, stream>>>(H, edge_cols, col_len, col_edge);
    decode_kernel<<<BATCH, 256, 0, stream>>>(r, alpha, beta, eta, qk,
                                             edge_cols, col_len, col_edge, out);
}

// Round 2
// 122.767 us; speedup vs baseline: 1.8511x; 1.8511x over previous
//
#include <hip/hip_runtime.h>
#include <hip/hip_bf16.h>
#include <math.h>

// Problem constants (from reference)
#define R_CHK   144
#define N_VAR   576
#define BATCH   512
#define ITERS   3
#define NLEV    16
#define ROW_DEG 15
#define N_EDGE  (R_CHK * ROW_DEG)   // 2160
#define MAXDEG  32
#define NWORDS  9                    // 576 / 64

// ---------------------------------------------------------------------------
// Kernel A: build sparse index from H via a 144x9 uint64 bitmask in LDS.
//   edge_cols[e]          : column of edge e (e = row*15 + k, cols ascending)
//   col_len[v]            : number of edges incident to column v
//   col_edge[v*MAXDEG+j]  : edge ids of column v, ascending row order
// ---------------------------------------------------------------------------
__launch_bounds__(N_VAR)
__global__ void build_index_kernel(const float* __restrict__ H,
                                   int* __restrict__ edge_cols,
                                   int* __restrict__ col_len,
                                   int* __restrict__ col_edge) {
    __shared__ unsigned long long s_bits[R_CHK][NWORDS];   // 10368 B
    __shared__ int s_ecol[N_EDGE];

    const int t    = threadIdx.x;      // 576 threads
    const int wave = t >> 6;           // 0..8
    const int lane = t & 63;

    // Phase 0: coalesced load of H, compress to bitmask via ballot.
    // Wave w covers columns [w*64, w*64+64) of every row.
    for (int i = 0; i < R_CHK; ++i) {
        float h = H[i * N_VAR + t];
        unsigned long long m = __ballot(h > 0.5f);
        if (lane == 0) s_bits[i][wave] = m;
    }
    __syncthreads();

    // Phase 1: per-row set-bit extraction (ascending column order).
    if (t < R_CHK) {
        int k = 0;
        for (int w = 0; w < NWORDS; ++w) {
            unsigned long long m = s_bits[t][w];
            while (m) {
                int b = __ffsll((long long)m) - 1;
                if (k < ROW_DEG) s_ecol[t * ROW_DEG + k] = w * 64 + b;
                ++k;
                m &= m - 1;
            }
        }
    }
    __syncthreads();

    // Write edge->col map (coalesced).
    for (int e = t; e < N_EDGE; e += N_VAR) edge_cols[e] = s_ecol[e];

    // Phase 2: per-column edge lists (ascending row order).
    // All 64 lanes of a wave share the same word index -> LDS broadcast.
    {
        const int w   = t >> 6;
        const int bit = t & 63;
        const unsigned long long vmask   = 1ull << bit;
        const unsigned long long lowmask = vmask - 1ull;
        int n = 0;
        for (int i = 0; i < R_CHK; ++i) {
            unsigned long long mw = s_bits[i][w];
            if (mw & vmask) {
                int rank = __popcll(mw & lowmask);
                for (int u = 0; u < w; ++u) rank += __popcll(s_bits[i][u]);
                if (n < MAXDEG) col_edge[t * MAXDEG + n] = i * ROW_DEG + rank;
                ++n;
            }
        }
        col_len[t] = (n < MAXDEG) ? n : MAXDEG;
    }
}

// ---------------------------------------------------------------------------
// Kernel B: one block per batch element; all messages live in LDS.
// ---------------------------------------------------------------------------
__launch_bounds__(256)
__global__ void decode_kernel(const float* __restrict__ r,
                              const float* __restrict__ alpha,
                              const float* __restrict__ beta,
                              const float* __restrict__ eta,
                              const float* __restrict__ qk,
                              const int* __restrict__ edge_cols,
                              const int* __restrict__ col_len,
                              const int* __restrict__ col_edge,
                              float* __restrict__ out) {
    __shared__ float sM[N_EDGE];
    __shared__ float sE[N_EDGE];
    __shared__ float scol[N_VAR];
    __shared__ float sr[N_VAR];
    __shared__ int   secol[N_EDGE];
    __shared__ float sqk[NLEV];
    __shared__ float sbnd[NLEV - 1];

    const int b = blockIdx.x;
    const int t = threadIdx.x;

    if (t < NLEV) sqk[t] = qk[t];
    __syncthreads();
    if (t < NLEV - 1) sbnd[t] = 0.5f * (sqk[t] + sqk[t + 1]);   // same as jnp
    for (int v = t; v < N_VAR; v += 256) sr[v] = r[b * N_VAR + v];
    for (int e = t; e < N_EDGE; e += 256) secol[e] = edge_cols[e];
    __syncthreads();
    for (int e = t; e < N_EDGE; e += 256) sM[e] = sr[secol[e]];  // M = H*r
    __syncthreads();

    for (int it = 0; it < ITERS; ++it) {
        const float a   = alpha[it];
        const float bta = beta[it];
        const float et  = eta[it];

        // ---- row phase: check-to-variable messages -----------------------
        if (t < R_CHK) {
            const int base = t * ROW_DEG;
            float vals[ROW_DEG];
            float m1 = INFINITY, m2 = INFINITY;
            float prod = 1.0f;
#pragma unroll
            for (int k = 0; k < ROW_DEG; ++k) {
                float M = sM[base + k];
                vals[k] = M;
                float ab = fabsf(M);
                if (ab < m1)      { m2 = m1; m1 = ab; }
                else if (ab < m2) { m2 = ab; }
                float s = (M > 0.0f) ? 1.0f : ((M < 0.0f) ? -1.0f : 0.0f);
                prod *= s;
            }
#pragma unroll
            for (int k = 0; k < ROW_DEG; ++k) {
                float M  = vals[k];
                float ab = fabsf(M);
                float mexcl = (ab == m1) ? m2 : m1;   // exact ==, matches jnp.where(mag==m1,...)
                float s  = (M > 0.0f) ? 1.0f : ((M < 0.0f) ? -1.0f : 0.0f);
                float E  = ((a * prod) * s) * fmaxf(mexcl - bta, 0.0f);
                // quantize: idx = #{ bnd[j] < eta*E }  (searchsorted side='left')
                float y = et * E;
                int idx = 0;
#pragma unroll
                for (int j = 0; j < NLEV - 1; ++j) idx += (y > sbnd[j]) ? 1 : 0;
                sE[base + k] = sqk[idx];
            }
        }
        __syncthreads();

        // ---- column phase: sum over checks (ascending row order) ---------
        for (int v = t; v < N_VAR; v += 256) {
            float sum = 0.0f;
            int n = col_len[v];
            const int* ce = col_edge + v * MAXDEG;
            for (int j = 0; j < n; ++j) sum += sE[ce[j]];
            scol[v] = sum;
        }
        __syncthreads();

        // ---- variable-to-check update (dead after last iteration) --------
        if (it < ITERS - 1) {
            for (int e = t; e < N_EDGE; e += 256) {
                int v = secol[e];
                float M = (sr[v] + scol[v]) - sE[e];
                float y = et * M;
                int idx = 0;
#pragma unroll
                for (int j = 0; j < NLEV - 1; ++j) idx += (y > sbnd[j]) ? 1 : 0;
                sM[e] = sqk[idx];
            }
            __syncthreads();
        }
    }

    // out = r + sum(E, axis=1)  (== r + col from last iteration)
    for (int v = t; v < N_VAR; v += 256) out[b * N_VAR + v] = sr[v] + scol[v];
}

// ---------------------------------------------------------------------------
extern "C" void kernel_launch(void* const* d_in, const int* in_sizes, int n_in,
                              void* d_out, int out_size, void* d_ws, size_t ws_size,
                              hipStream_t stream) {
    const float* r     = (const float*)d_in[0];
    const float* alpha = (const float*)d_in[1];
    const float* beta  = (const float*)d_in[2];
    const float* eta   = (const float*)d_in[3];
    const float* qk    = (const float*)d_in[4];
    const float* H     = (const float*)d_in[5];
    float* out = (float*)d_out;

    // workspace layout
    int* edge_cols = (int*)d_ws;                    // N_EDGE ints
    int* col_len   = edge_cols + N_EDGE;            // N_VAR ints
    int* col_edge  = col_len + N_VAR;               // N_VAR*MAXDEG ints

    build_index_kernel<<<1, N_VAR, 0, stream>>>(H, edge_cols, col_len, col_edge);
    decode_kernel<<<BATCH, 256, 0, stream>>>(r, alpha, beta, eta, qk,
                                             edge_cols, col_len, col_edge, out);
}

// Round 3
// 66.390 us; speedup vs baseline: 3.4230x; 1.8492x over previous
//
#include <hip/hip_runtime.h>
#include <hip/hip_bf16.h>
#include <math.h>

// Problem constants (from reference)
#define R_CHK   144
#define N_VAR   576
#define BATCH   512
#define ITERS   3
#define NLEV    16
#define ROW_DEG 15
#define N_EDGE  (R_CHK * ROW_DEG)   // 2160
#define MAXDEG  32
#define NWORDS  9                    // 576 / 64
#define CHUNK   16                   // rows per pipelined chunk (144 = 9*16)

// ---------------------------------------------------------------------------
// Kernel A: build sparse index from H via a 144x9 uint64 bitmask in LDS.
// Pipelined: loads are issued in chunks of 16 independent rows so the
// compiler can keep many vmem ops in flight (was: 144 serial round-trips).
// ---------------------------------------------------------------------------
__launch_bounds__(N_VAR)
__global__ void build_index_kernel(const float* __restrict__ H,
                                   int* __restrict__ edge_cols,
                                   int* __restrict__ col_len,
                                   int* __restrict__ col_edge) {
    __shared__ unsigned long long s_bits[R_CHK][NWORDS];   // 10368 B
    __shared__ int s_pref[R_CHK][NWORDS];                  //  5184 B
    __shared__ int s_ecol[N_EDGE];                         //  8640 B

    const int t    = threadIdx.x;      // 576 threads
    const int wave = t >> 6;           // 0..8
    const int lane = t & 63;

    // Phase 0: coalesced load of H, compress to bitmask via ballot.
    // 16 independent loads in flight per chunk -> latency pipelined.
    for (int i0 = 0; i0 < R_CHK; i0 += CHUNK) {
        float h[CHUNK];
#pragma unroll
        for (int j = 0; j < CHUNK; ++j) h[j] = H[(i0 + j) * N_VAR + t];
#pragma unroll
        for (int j = 0; j < CHUNK; ++j) {
            unsigned long long m = __ballot(h[j] > 0.5f);
            if (lane == 0) s_bits[i0 + j][wave] = m;
        }
    }
    __syncthreads();

    // Phase 1a: per-row set-bit extraction (ascending column order).
    if (t < R_CHK) {
        int k = 0;
        for (int w = 0; w < NWORDS; ++w) {
            unsigned long long m = s_bits[t][w];
            while (m) {
                int b = __ffsll((long long)m) - 1;
                if (k < ROW_DEG) s_ecol[t * ROW_DEG + k] = w * 64 + b;
                ++k;
                m &= m - 1;
            }
        }
    }

    // Phase 1b: per-row word-prefix popcounts (all 576 threads, 1296 items).
    for (int idx = t; idx < R_CHK * NWORDS; idx += N_VAR) {
        int i = idx / NWORDS, w = idx % NWORDS;
        int p = 0;
        for (int u = 0; u < w; ++u) p += __popcll(s_bits[i][u]);
        s_pref[i][w] = p;
    }
    __syncthreads();

    // Write edge->col map (coalesced).
    for (int e = t; e < N_EDGE; e += N_VAR) edge_cols[e] = s_ecol[e];

    // Phase 2: per-column edge lists (ascending row order), chunk-pipelined.
    {
        const int w   = t >> 6;
        const int bit = t & 63;
        const unsigned long long vmask   = 1ull << bit;
        const unsigned long long lowmask = vmask - 1ull;
        int n = 0;
        for (int i0 = 0; i0 < R_CHK; i0 += CHUNK) {
            unsigned long long mw[CHUNK];
            int pf[CHUNK];
#pragma unroll
            for (int j = 0; j < CHUNK; ++j) {
                mw[j] = s_bits[i0 + j][w];
                pf[j] = s_pref[i0 + j][w];
            }
#pragma unroll
            for (int j = 0; j < CHUNK; ++j) {
                if (mw[j] & vmask) {
                    int rank = pf[j] + __popcll(mw[j] & lowmask);
                    if (n < MAXDEG) col_edge[t * MAXDEG + n] = (i0 + j) * ROW_DEG + rank;
                    ++n;
                }
            }
        }
        col_len[t] = (n < MAXDEG) ? n : MAXDEG;
    }
}

// ---------------------------------------------------------------------------
// Kernel B: one block per batch element; all messages live in LDS.
// ---------------------------------------------------------------------------
__launch_bounds__(256)
__global__ void decode_kernel(const float* __restrict__ r,
                              const float* __restrict__ alpha,
                              const float* __restrict__ beta,
                              const float* __restrict__ eta,
                              const float* __restrict__ qk,
                              const int* __restrict__ edge_cols,
                              const int* __restrict__ col_len,
                              const int* __restrict__ col_edge,
                              float* __restrict__ out) {
    __shared__ float sM[N_EDGE];
    __shared__ float sE[N_EDGE];
    __shared__ float scol[N_VAR];
    __shared__ float sr[N_VAR];
    __shared__ int   secol[N_EDGE];
    __shared__ float sqk[NLEV];
    __shared__ float sbnd[NLEV - 1];

    const int b = blockIdx.x;
    const int t = threadIdx.x;

    if (t < NLEV) sqk[t] = qk[t];
    __syncthreads();
    if (t < NLEV - 1) sbnd[t] = 0.5f * (sqk[t] + sqk[t + 1]);   // same as jnp
    for (int v = t; v < N_VAR; v += 256) sr[v] = r[b * N_VAR + v];
    for (int e = t; e < N_EDGE; e += 256) secol[e] = edge_cols[e];
    __syncthreads();
    for (int e = t; e < N_EDGE; e += 256) sM[e] = sr[secol[e]];  // M = H*r
    __syncthreads();

    for (int it = 0; it < ITERS; ++it) {
        const float a   = alpha[it];
        const float bta = beta[it];
        const float et  = eta[it];

        // ---- row phase: check-to-variable messages -----------------------
        if (t < R_CHK) {
            const int base = t * ROW_DEG;
            float vals[ROW_DEG];
            float m1 = INFINITY, m2 = INFINITY;
            float prod = 1.0f;
#pragma unroll
            for (int k = 0; k < ROW_DEG; ++k) {
                float M = sM[base + k];
                vals[k] = M;
                float ab = fabsf(M);
                if (ab < m1)      { m2 = m1; m1 = ab; }
                else if (ab < m2) { m2 = ab; }
                float s = (M > 0.0f) ? 1.0f : ((M < 0.0f) ? -1.0f : 0.0f);
                prod *= s;
            }
#pragma unroll
            for (int k = 0; k < ROW_DEG; ++k) {
                float M  = vals[k];
                float ab = fabsf(M);
                float mexcl = (ab == m1) ? m2 : m1;   // exact ==, matches jnp.where(mag==m1,...)
                float s  = (M > 0.0f) ? 1.0f : ((M < 0.0f) ? -1.0f : 0.0f);
                float E  = ((a * prod) * s) * fmaxf(mexcl - bta, 0.0f);
                // quantize: idx = #{ bnd[j] < eta*E }  (searchsorted side='left')
                float y = et * E;
                int idx = 0;
#pragma unroll
                for (int j = 0; j < NLEV - 1; ++j) idx += (y > sbnd[j]) ? 1 : 0;
                sE[base + k] = sqk[idx];
            }
        }
        __syncthreads();

        // ---- column phase: sum over checks (ascending row order) ---------
        for (int v = t; v < N_VAR; v += 256) {
            float sum = 0.0f;
            int n = col_len[v];
            const int* ce = col_edge + v * MAXDEG;
            for (int j = 0; j < n; ++j) sum += sE[ce[j]];
            scol[v] = sum;
        }
        __syncthreads();

        // ---- variable-to-check update (dead after last iteration) --------
        if (it < ITERS - 1) {
            for (int e = t; e < N_EDGE; e += 256) {
                int v = secol[e];
                float M = (sr[v] + scol[v]) - sE[e];
                float y = et * M;
                int idx = 0;
#pragma unroll
                for (int j = 0; j < NLEV - 1; ++j) idx += (y > sbnd[j]) ? 1 : 0;
                sM[e] = sqk[idx];
            }
            __syncthreads();
        }
    }

    // out = r + sum(E, axis=1)  (== r + col from last iteration)
    for (int v = t; v < N_VAR; v += 256) out[b * N_VAR + v] = sr[v] + scol[v];
}

// ---------------------------------------------------------------------------
extern "C" void kernel_launch(void* const* d_in, const int* in_sizes, int n_in,
                              void* d_out, int out_size, void* d_ws, size_t ws_size,
                              hipStream_t stream) {
    const float* r     = (const float*)d_in[0];
    const float* alpha = (const float*)d_in[1];
    const float* beta  = (const float*)d_in[2];
    const float* eta   = (const float*)d_in[3];
    const float* qk    = (const float*)d_in[4];
    const float* H     = (const float*)d_in[5];
    float* out = (float*)d_out;

    // workspace layout
    int* edge_cols = (int*)d_ws;                    // N_EDGE ints
    int* col_len   = edge_cols + N_EDGE;            // N_VAR ints
    int* col_edge  = col_len + N_VAR;               // N_VAR*MAXDEG ints

    build_index_kernel<<<1, N_VAR, 0, stream>>>(H, edge_cols, col_len, col_edge);
    decode_kernel<<<BATCH, 256, 0, stream>>>(r, alpha, beta, eta, qk,
                                             edge_cols, col_len, col_edge, out);
}

// Round 4
// 50.862 us; speedup vs baseline: 4.4681x; 1.3053x over previous
//
#include <hip/hip_runtime.h>
#include <hip/hip_bf16.h>
#include <math.h>

// Problem constants (from reference)
#define R_CHK   144
#define N_VAR   576
#define BATCH   512
#define ITERS   3
#define NLEV    16
#define ROW_DEG 15
#define N_EDGE  (R_CHK * ROW_DEG)   // 2160
#define NWORDS  9                    // 576 / 64

// ---------------------------------------------------------------------------
// K1: one wave per row -> 9 ballot words + row edge-column list.
// ---------------------------------------------------------------------------
__launch_bounds__(64)
__global__ void k1_bitmask(const float* __restrict__ H,
                           unsigned long long* __restrict__ bits,
                           int* __restrict__ edge_cols) {
    const int i    = blockIdx.x;
    const int lane = threadIdx.x;

    float h[NWORDS];
#pragma unroll
    for (int s = 0; s < NWORDS; ++s) h[s] = H[i * N_VAR + s * 64 + lane];

    unsigned long long m[NWORDS];
#pragma unroll
    for (int s = 0; s < NWORDS; ++s) m[s] = __ballot(h[s] > 0.5f);

#pragma unroll
    for (int s = 0; s < NWORDS; ++s)
        if (lane == s) bits[i * NWORDS + s] = m[s];

    if (lane == 0) {
        int k = 0;
#pragma unroll
        for (int s = 0; s < NWORDS; ++s) {
            unsigned long long mm = m[s];
            while (mm) {
                int b = __ffsll((long long)mm) - 1;
                if (k < ROW_DEG) edge_cols[i * ROW_DEG + k] = s * 64 + b;
                ++k;
                mm &= mm - 1;
            }
        }
    }
}

// ---------------------------------------------------------------------------
// K2: bitmask -> CSR column lists (ascending row order), exclusive-scan ptr.
// ---------------------------------------------------------------------------
__launch_bounds__(N_VAR)
__global__ void k2_csr(const unsigned long long* __restrict__ bits,
                       int* __restrict__ col_ptr,
                       int* __restrict__ col_csr) {
    __shared__ unsigned long long sb[R_CHK * NWORDS];   // 10368 B
    __shared__ int spref[R_CHK * NWORDS];               //  5184 B
    __shared__ int sscan[2][N_VAR];                     //  4608 B

    const int t = threadIdx.x;   // 576 threads

    for (int e = t; e < R_CHK * NWORDS; e += N_VAR) sb[e] = bits[e];
    __syncthreads();

    // per-row word-prefix popcounts
    for (int idx = t; idx < R_CHK * NWORDS; idx += N_VAR) {
        int i = idx / NWORDS, w = idx % NWORDS;
        int p = 0;
        for (int u = 0; u < w; ++u) p += __popcll(sb[i * NWORDS + u]);
        spref[idx] = p;
    }

    // column degree count (chunk-pipelined LDS reads)
    const int w   = t >> 6;
    const int bit = t & 63;
    const unsigned long long vmask   = 1ull << bit;
    const unsigned long long lowmask = vmask - 1ull;
    int n = 0;
    for (int i0 = 0; i0 < R_CHK; i0 += 16) {
        unsigned long long mw[16];
#pragma unroll
        for (int j = 0; j < 16; ++j) mw[j] = sb[(i0 + j) * NWORDS + w];
#pragma unroll
        for (int j = 0; j < 16; ++j) n += (int)((mw[j] >> bit) & 1ull);
    }
    __syncthreads();
    sscan[0][t] = n;
    __syncthreads();

    // Hillis-Steele inclusive scan (double buffer)
    int src = 0;
    for (int off = 1; off < N_VAR; off <<= 1) {
        int v = sscan[src][t];
        if (t >= off) v += sscan[src][t - off];
        sscan[src ^ 1][t] = v;
        src ^= 1;
        __syncthreads();
    }

    const int myptr = sscan[src][t] - n;   // exclusive
    col_ptr[t] = myptr;
    if (t == N_VAR - 1) col_ptr[N_VAR] = sscan[src][t];

    // CSR fill (ascending row order)
    int p = myptr;
    for (int i0 = 0; i0 < R_CHK; i0 += 16) {
        unsigned long long mw[16];
        int pf[16];
#pragma unroll
        for (int j = 0; j < 16; ++j) {
            mw[j] = sb[(i0 + j) * NWORDS + w];
            pf[j] = spref[(i0 + j) * NWORDS + w];
        }
#pragma unroll
        for (int j = 0; j < 16; ++j) {
            if (mw[j] & vmask) {
                int rank = pf[j] + __popcll(mw[j] & lowmask);
                col_csr[p++] = (i0 + j) * ROW_DEG + rank;
            }
        }
    }
}

// ---------------------------------------------------------------------------
// Decode: one block per batch. Row phase fused with M-update (M, Eq live in
// registers); quantizer boundaries in VGPRs; qk lookup via __shfl.
// ---------------------------------------------------------------------------
__launch_bounds__(256)
__global__ void decode_kernel(const float* __restrict__ r,
                              const float* __restrict__ alpha,
                              const float* __restrict__ beta,
                              const float* __restrict__ eta,
                              const float* __restrict__ qk,
                              const int* __restrict__ edge_cols,
                              const int* __restrict__ col_ptr,
                              const int* __restrict__ col_csr,
                              float* __restrict__ out) {
    __shared__ float sE[N_EDGE];      // quantized E, indexed by edge id
    __shared__ float sr[N_VAR];       // channel values
    __shared__ float st[N_VAR];       // r + colsum
    __shared__ int   s_csr[N_EDGE];
    __shared__ int   s_ptr[N_VAR + 1];

    const int b = blockIdx.x;
    const int t = threadIdx.x;

    // Register-resident quantizer state (same arithmetic as before).
    const float qv = qk[t & 15];          // lane L holds qk[L&15]
    float bnd[NLEV - 1];
#pragma unroll
    for (int j = 0; j < NLEV - 1; ++j) bnd[j] = 0.5f * (qk[j] + qk[j + 1]);

    float av[ITERS], bv[ITERS], ev[ITERS];
#pragma unroll
    for (int i = 0; i < ITERS; ++i) { av[i] = alpha[i]; bv[i] = beta[i]; ev[i] = eta[i]; }

    // Stage index + inputs.
    for (int e = t; e < N_EDGE; e += 256) s_csr[e] = col_csr[e];
    for (int v = t; v < N_VAR + 1; v += 256) s_ptr[v] = col_ptr[v];
    for (int v = t; v < N_VAR; v += 256) sr[v] = r[b * N_VAR + v];

    const bool isrow = (t < R_CHK);
    int cols[ROW_DEG];
    if (isrow) {
#pragma unroll
        for (int k = 0; k < ROW_DEG; ++k) cols[k] = edge_cols[t * ROW_DEG + k];
    }
    __syncthreads();

    float M[ROW_DEG], Eq[ROW_DEG];
    if (isrow) {
#pragma unroll
        for (int k = 0; k < ROW_DEG; ++k) M[k] = sr[cols[k]];   // M = H*r
    }

#pragma unroll
    for (int it = 0; it < ITERS; ++it) {
        const float a   = av[it];
        const float bta = bv[it];
        const float et  = ev[it];

        if (isrow) {
            // ---- fused M-update from previous iteration (eta_{it-1}) -----
            if (it > 0) {
                const float etp = ev[it - 1];
#pragma unroll
                for (int k = 0; k < ROW_DEG; ++k) {
                    float x = st[cols[k]] - Eq[k];          // (r+col) - E
                    float y = etp * x;
                    int idx = 0;
#pragma unroll
                    for (int j = 0; j < NLEV - 1; ++j) idx += (y > bnd[j]) ? 1 : 0;
                    M[k] = __shfl(qv, idx);
                }
            }

            // ---- row phase: min2 / sign product ---------------------------
            float m1 = INFINITY, m2 = INFINITY;
            float prod = 1.0f;
#pragma unroll
            for (int k = 0; k < ROW_DEG; ++k) {
                float ab = fabsf(M[k]);
                if (ab < m1)      { m2 = m1; m1 = ab; }
                else if (ab < m2) { m2 = ab; }
                float s = (M[k] > 0.0f) ? 1.0f : ((M[k] < 0.0f) ? -1.0f : 0.0f);
                prod *= s;
            }
#pragma unroll
            for (int k = 0; k < ROW_DEG; ++k) {
                float ab = fabsf(M[k]);
                float mexcl = (ab == m1) ? m2 : m1;
                float s  = (M[k] > 0.0f) ? 1.0f : ((M[k] < 0.0f) ? -1.0f : 0.0f);
                float E  = ((a * prod) * s) * fmaxf(mexcl - bta, 0.0f);
                float y = et * E;
                int idx = 0;
#pragma unroll
                for (int j = 0; j < NLEV - 1; ++j) idx += (y > bnd[j]) ? 1 : 0;
                float eq = __shfl(qv, idx);
                Eq[k] = eq;
                sE[t * ROW_DEG + k] = eq;
            }
        }
        __syncthreads();

        // ---- column phase: ordered sum + st = r + col ---------------------
        for (int v = t; v < N_VAR; v += 256) {
            float sum = 0.0f;
            const int p0 = s_ptr[v], p1 = s_ptr[v + 1];
            for (int j = p0; j < p1; ++j) sum += sE[s_csr[j]];
            float stv = sr[v] + sum;
            st[v] = stv;
            if (it == ITERS - 1) out[b * N_VAR + v] = stv;
        }
        if (it < ITERS - 1) __syncthreads();
    }
}

// ---------------------------------------------------------------------------
extern "C" void kernel_launch(void* const* d_in, const int* in_sizes, int n_in,
                              void* d_out, int out_size, void* d_ws, size_t ws_size,
                              hipStream_t stream) {
    const float* r     = (const float*)d_in[0];
    const float* alpha = (const float*)d_in[1];
    const float* beta  = (const float*)d_in[2];
    const float* eta   = (const float*)d_in[3];
    const float* qk    = (const float*)d_in[4];
    const float* H     = (const float*)d_in[5];
    float* out = (float*)d_out;

    // workspace layout (bits first: 8B aligned)
    unsigned long long* bits = (unsigned long long*)d_ws;     // 1296 u64
    int* edge_cols = (int*)(bits + R_CHK * NWORDS);           // 2160 ints
    int* col_ptr   = edge_cols + N_EDGE;                      // 577 ints
    int* col_csr   = col_ptr + (N_VAR + 1);                   // 2160 ints

    k1_bitmask<<<R_CHK, 64, 0, stream>>>(H, bits, edge_cols);
    k2_csr<<<1, N_VAR, 0, stream>>>(bits, col_ptr, col_csr);
    decode_kernel<<<BATCH, 256, 0, stream>>>(r, alpha, beta, eta, qk,
                                             edge_cols, col_ptr, col_csr, out);
}

// Round 5
// 42.974 us; speedup vs baseline: 5.2882x; 1.1835x over previous
//
#include <hip/hip_runtime.h>
#include <hip/hip_bf16.h>
#include <math.h>

// Problem constants (from reference)
#define R_CHK   144
#define N_VAR   576
#define BATCH   512
#define ITERS   3
#define NLEV    16
#define ROW_DEG 15
#define N_EDGE  (R_CHK * ROW_DEG)   // 2160
#define NWORDS  9                    // 576 / 64
#define DEG_PAD 16                   // max column degree (binom(144, 15/576), max ~11)

// ---------------------------------------------------------------------------
// K1: one wave per row -> 9 ballot words + row edge-column list.
// ---------------------------------------------------------------------------
__launch_bounds__(64)
__global__ void k1_bitmask(const float* __restrict__ H,
                           unsigned long long* __restrict__ bits,
                           int* __restrict__ edge_cols) {
    const int i    = blockIdx.x;
    const int lane = threadIdx.x;

    float h[NWORDS];
#pragma unroll
    for (int s = 0; s < NWORDS; ++s) h[s] = H[i * N_VAR + s * 64 + lane];

    unsigned long long m[NWORDS];
#pragma unroll
    for (int s = 0; s < NWORDS; ++s) m[s] = __ballot(h[s] > 0.5f);

#pragma unroll
    for (int s = 0; s < NWORDS; ++s)
        if (lane == s) bits[i * NWORDS + s] = m[s];

    if (lane == 0) {
        int k = 0;
#pragma unroll
        for (int s = 0; s < NWORDS; ++s) {
            unsigned long long mm = m[s];
            while (mm) {
                int b = __ffsll((long long)mm) - 1;
                if (k < ROW_DEG) edge_cols[i * ROW_DEG + k] = s * 64 + b;
                ++k;
                mm &= mm - 1;
            }
        }
    }
}

// ---------------------------------------------------------------------------
// K2: bitmask -> fixed-degree column table (ascending row order, padded with
// dummy edge id N_EDGE which maps to a zero slot in decode's sE).
// ---------------------------------------------------------------------------
__launch_bounds__(N_VAR)
__global__ void k2_coltab(const unsigned long long* __restrict__ bits,
                          int* __restrict__ col_edge) {
    __shared__ unsigned long long sb[R_CHK * NWORDS];   // 10368 B
    __shared__ int spref[R_CHK * NWORDS];               //  5184 B

    const int t = threadIdx.x;   // 576 threads

    for (int e = t; e < R_CHK * NWORDS; e += N_VAR) sb[e] = bits[e];
    __syncthreads();

    // per-row word-prefix popcounts
    for (int idx = t; idx < R_CHK * NWORDS; idx += N_VAR) {
        int i = idx / NWORDS, w = idx % NWORDS;
        int p = 0;
        for (int u = 0; u < w; ++u) p += __popcll(sb[i * NWORDS + u]);
        spref[idx] = p;
    }
    __syncthreads();

    // per-column fill (chunk-pipelined LDS reads; ascending row order)
    const int w   = t >> 6;
    const int bit = t & 63;
    const unsigned long long vmask   = 1ull << bit;
    const unsigned long long lowmask = vmask - 1ull;
    int n = 0;
    for (int i0 = 0; i0 < R_CHK; i0 += 16) {
        unsigned long long mw[16];
        int pf[16];
#pragma unroll
        for (int j = 0; j < 16; ++j) {
            mw[j] = sb[(i0 + j) * NWORDS + w];
            pf[j] = spref[(i0 + j) * NWORDS + w];
        }
#pragma unroll
        for (int j = 0; j < 16; ++j) {
            if (mw[j] & vmask) {
                int rank = pf[j] + __popcll(mw[j] & lowmask);
                if (n < DEG_PAD) col_edge[t * DEG_PAD + n] = (i0 + j) * ROW_DEG + rank;
                ++n;
            }
        }
    }
    for (int j = n; j < DEG_PAD; ++j) col_edge[t * DEG_PAD + j] = N_EDGE; // pad -> zero slot
}

// ---------------------------------------------------------------------------
// Decode: one block per batch. Messages and column table in registers;
// col phase fully unrolled over fixed degree (latency-pipelined).
// ---------------------------------------------------------------------------
__launch_bounds__(256)
__global__ void decode_kernel(const float* __restrict__ r,
                              const float* __restrict__ alpha,
                              const float* __restrict__ beta,
                              const float* __restrict__ eta,
                              const float* __restrict__ qk,
                              const int* __restrict__ edge_cols,
                              const int* __restrict__ col_edge,
                              float* __restrict__ out) {
    __shared__ float sE[N_EDGE + 1];  // +1: zero slot for padded column reads
    __shared__ float sr[N_VAR];
    __shared__ float st[N_VAR];

    const int b = blockIdx.x;
    const int t = threadIdx.x;

    // Quantizer state in registers (exact, same arithmetic as reference).
    const float qv = qk[t & 15];          // lane L holds qk[L&15] -> __shfl lookup
    float bnd[NLEV - 1];
#pragma unroll
    for (int j = 0; j < NLEV - 1; ++j) bnd[j] = 0.5f * (qk[j] + qk[j + 1]);

    float av[ITERS], bv[ITERS], ev[ITERS];
#pragma unroll
    for (int i = 0; i < ITERS; ++i) { av[i] = alpha[i]; bv[i] = beta[i]; ev[i] = eta[i]; }

    // Register-resident column table: thread t owns columns t, t+256 (+512 if t<64).
    int ce0[DEG_PAD], ce1[DEG_PAD], ce2[DEG_PAD];
#pragma unroll
    for (int j = 0; j < DEG_PAD; ++j) ce0[j] = col_edge[t * DEG_PAD + j];
#pragma unroll
    for (int j = 0; j < DEG_PAD; ++j) ce1[j] = col_edge[(t + 256) * DEG_PAD + j];
    if (t < N_VAR - 512) {
#pragma unroll
        for (int j = 0; j < DEG_PAD; ++j) ce2[j] = col_edge[(t + 512) * DEG_PAD + j];
    }

    const bool isrow = (t < R_CHK);
    int cols[ROW_DEG];
    if (isrow) {
#pragma unroll
        for (int k = 0; k < ROW_DEG; ++k) cols[k] = edge_cols[t * ROW_DEG + k];
    }

    for (int v = t; v < N_VAR; v += 256) sr[v] = r[b * N_VAR + v];
    if (t == 0) sE[N_EDGE] = 0.0f;
    __syncthreads();

    float M[ROW_DEG], Eq[ROW_DEG];
    if (isrow) {
#pragma unroll
        for (int k = 0; k < ROW_DEG; ++k) M[k] = sr[cols[k]];   // M = H*r
    }

#pragma unroll
    for (int it = 0; it < ITERS; ++it) {
        const float a   = av[it];
        const float bta = bv[it];
        const float et  = ev[it];

        if (isrow) {
            // ---- fused M-update from previous iteration (eta_{it-1}) -----
            if (it > 0) {
                const float etp = ev[it - 1];
#pragma unroll
                for (int k = 0; k < ROW_DEG; ++k) {
                    float x = st[cols[k]] - Eq[k];          // (r+col) - E
                    float y = etp * x;
                    int idx = 0;
#pragma unroll
                    for (int j = 0; j < NLEV - 1; ++j) idx += (y > bnd[j]) ? 1 : 0;
                    M[k] = __shfl(qv, idx);
                }
            }

            // ---- signs (kept) + tree sign-product (order-exact: ±1/0) ----
            float sg[ROW_DEG];
#pragma unroll
            for (int k = 0; k < ROW_DEG; ++k)
                sg[k] = (M[k] > 0.0f) ? 1.0f : ((M[k] < 0.0f) ? -1.0f : 0.0f);
            float q0 = sg[0] * sg[1],  q1 = sg[2] * sg[3];
            float q2 = sg[4] * sg[5],  q3 = sg[6] * sg[7];
            float q4 = sg[8] * sg[9],  q5 = sg[10] * sg[11];
            float q6 = sg[12] * sg[13], q7 = sg[14];
            float r0 = q0 * q1, r1 = q2 * q3, r2 = q4 * q5, r3 = q6 * q7;
            const float prod = (r0 * r1) * (r2 * r3);

            // ---- tree min2 over |M| (exact: same multiset selection) -----
            float a1[8], a2[8];
#pragma unroll
            for (int k = 0; k < 7; ++k) {
                float x = fabsf(M[2 * k]), y = fabsf(M[2 * k + 1]);
                a1[k] = fminf(x, y); a2[k] = fmaxf(x, y);
            }
            a1[7] = fabsf(M[14]); a2[7] = INFINITY;
#pragma unroll
            for (int s = 4; s >= 1; s >>= 1) {
#pragma unroll
                for (int k = 0; k < 4; ++k) {
                    if (k < s) {
                        float lo = fminf(a1[k], a1[k + s]);
                        float hi = fminf(fmaxf(a1[k], a1[k + s]), fminf(a2[k], a2[k + s]));
                        a1[k] = lo; a2[k] = hi;
                    }
                }
            }
            const float m1 = a1[0], m2 = a2[0];

            // ---- E + quantize, write sE ----------------------------------
            const float ap = a * prod;
#pragma unroll
            for (int k = 0; k < ROW_DEG; ++k) {
                float ab = fabsf(M[k]);
                float mexcl = (ab == m1) ? m2 : m1;
                float E = (ap * sg[k]) * fmaxf(mexcl - bta, 0.0f);
                float y = et * E;
                int idx = 0;
#pragma unroll
                for (int j = 0; j < NLEV - 1; ++j) idx += (y > bnd[j]) ? 1 : 0;
                float eq = __shfl(qv, idx);
                Eq[k] = eq;
                sE[t * ROW_DEG + k] = eq;
            }
        }
        __syncthreads();

        // ---- column phase: fixed-degree sums (all reads independent) -----
        {
            float s0 = 0.0f, s1 = 0.0f, s2 = 0.0f;
#pragma unroll
            for (int j = 0; j < DEG_PAD; ++j) s0 += sE[ce0[j]];
#pragma unroll
            for (int j = 0; j < DEG_PAD; ++j) s1 += sE[ce1[j]];
            if (t < N_VAR - 512) {
#pragma unroll
                for (int j = 0; j < DEG_PAD; ++j) s2 += sE[ce2[j]];
            }
            float t0 = sr[t] + s0;
            float t1 = sr[t + 256] + s1;
            st[t] = t0;
            st[t + 256] = t1;
            float t2 = 0.0f;
            if (t < N_VAR - 512) {
                t2 = sr[t + 512] + s2;
                st[t + 512] = t2;
            }
            if (it == ITERS - 1) {
                out[b * N_VAR + t] = t0;
                out[b * N_VAR + t + 256] = t1;
                if (t < N_VAR - 512) out[b * N_VAR + t + 512] = t2;
            }
        }
        if (it < ITERS - 1) __syncthreads();
    }
}

// ---------------------------------------------------------------------------
extern "C" void kernel_launch(void* const* d_in, const int* in_sizes, int n_in,
                              void* d_out, int out_size, void* d_ws, size_t ws_size,
                              hipStream_t stream) {
    const float* r     = (const float*)d_in[0];
    const float* alpha = (const float*)d_in[1];
    const float* beta  = (const float*)d_in[2];
    const float* eta   = (const float*)d_in[3];
    const float* qk    = (const float*)d_in[4];
    const float* H     = (const float*)d_in[5];
    float* out = (float*)d_out;

    // workspace layout (bits first: 8B aligned)
    unsigned long long* bits = (unsigned long long*)d_ws;     // 1296 u64
    int* edge_cols = (int*)(bits + R_CHK * NWORDS);           // 2160 ints
    int* col_edge  = edge_cols + N_EDGE;                      // 576*16 ints

    k1_bitmask<<<R_CHK, 64, 0, stream>>>(H, bits, edge_cols);
    k2_coltab<<<1, N_VAR, 0, stream>>>(bits, col_edge);
    decode_kernel<<<BATCH, 256, 0, stream>>>(r, alpha, beta, eta, qk,
                                             edge_cols, col_edge, out);
}